// Round 15
// baseline (138.935 us; speedup 1.0000x reference)
//
#include <hip/hip_runtime.h>

typedef __attribute__((ext_vector_type(8))) _Float16 f16x8;
typedef __attribute__((ext_vector_type(4))) float    f32x4;
typedef __attribute__((ext_vector_type(4))) int      i32x4;

#define IN_F   4096
#define OUT_F  4096
#define NGRP   32
#define NKT    64          /* K-tiles of 64 */

#define GLOAD16(gsrc, ldst)                                                   \
    __builtin_amdgcn_global_load_lds(                                         \
        (const __attribute__((address_space(1))) unsigned int*)(gsrc),        \
        (__attribute__((address_space(3))) unsigned int*)(ldst), 16, 0, 0)

#define CFENCE  asm volatile("" ::: "memory")
#define BARRIER do { CFENCE; __builtin_amdgcn_s_barrier(); CFENCE; } while (0)
#define VMW6    asm volatile("s_waitcnt vmcnt(6)" ::: "memory")
#define VMW8    asm volatile("s_waitcnt vmcnt(8)" ::: "memory")

// ---------------- fused prepass: X fp32->f16 and int4 dequant->f16 ----------
__global__ __launch_bounds__(256)
void prep(const float* __restrict__ X, const int* __restrict__ QW,
          const float* __restrict__ S, _Float16* __restrict__ XF,
          _Float16* __restrict__ WF) {
    if (blockIdx.x < 8192) {
        size_t i = ((size_t)blockIdx.x * 256 + threadIdx.x) * 8;
        f32x4 a = *(const f32x4*)(X + i);
        f32x4 b = *(const f32x4*)(X + i + 4);
        f16x8 h;
        h[0] = (_Float16)a[0]; h[1] = (_Float16)a[1];
        h[2] = (_Float16)a[2]; h[3] = (_Float16)a[3];
        h[4] = (_Float16)b[0]; h[5] = (_Float16)b[1];
        h[6] = (_Float16)b[2]; h[7] = (_Float16)b[3];
        *(f16x8*)(XF + i) = h;
    } else {
        size_t t  = ((size_t)blockIdx.x - 8192) * 256 + threadIdx.x;
        size_t jj = t * 4;                   // int32 index; 2048 per row
        size_t o  = jj >> 11;
        size_t jr = jj & 2047;
        const float s = S[o * NGRP + (jr >> 6)];   // group const across 4 int32
        i32x4 q = *(const i32x4*)(QW + jj);
        f16x8 h;
#pragma unroll
        for (int j = 0; j < 4; ++j) {
            const int v = q[j];
            h[2 * j]     = (_Float16)((float)(((v >> 4) & 15) - 8) * s);
            h[2 * j + 1] = (_Float16)((float)((v & 15) - 8) * s);
        }
        *(f16x8*)(WF + jj * 2) = h;
    }
}

// -------- main GEMM: 256^2, BK=64, 8-phase, READ-AHEAD-BY-ONE-PHASE --------
// Each phase issues the ds_reads feeding the NEXT phase's MFMA; the MFMA
// consumes regs read one phase (+barrier) earlier -> lgkm wait ~0 and this
// phase's LDS service overlaps this phase's MFMA (no SCHED0 -- r8's pinning
// was the suspected killer; register alternation aA/aB + bA/bB, each
// reloaded >=1 full phase after its last consume).
// Reads:  prevP7:{A0b0,B0b0} P0:{B1b0} P1:{A1b0} P3:{A0b1,B0b1} P4:{B1b1}
//         P5:{A1b1} P7:{A0b0',B0b0'}   (4/8/12 per phase)
// Stages (region free only AFTER its consuming phase's barrier):
//         P1:A0->b0  P2:B0->b0  P3:B1,A1->b0  P5:A0,B0->b1  P6:B1->b1  P7:A1->b1
// vmcnt (in-order keep-sets, all leads >=3 phases ~1600cyc >= HBM latency):
//   P2-end VMW6: out prevP5(4),prevP6(2),prevP7(2),P1(2),P2(2)=12 -> keep
//     {P2,P1,prevP7} -> b1.{A0,B0,B1} published for P3/P4 reads.
//   P4-end VMW6: out prevP7(2),P1(2),P2(2),P3(4)=10 -> keep {P3,P2} ->
//     b1.A1 published for P5 read.
//   P6-end VMW6: out P2(2),P3(4),P5(4),P6(2) minus retired = P3(4),P5(4),
//     P6(2)=10 -> keep {P5,P6} -> b0(t+2) complete, published for P7 read.
__global__ __launch_bounds__(512, 2)
void gemm_ra(const _Float16* __restrict__ A,
             const _Float16* __restrict__ B,
             float*          __restrict__ C)
{
    extern __shared__ char LDSc[];
    char* const ldsA = LDSc;
    char* const ldsB = LDSc + 65536;

    const int tid  = threadIdx.x;
    const int lane = tid & 63;
    const int wid  = tid >> 6;
    const int wm   = wid >> 2;          // 0..1
    const int wn   = wid & 3;           // 0..3

    const int bid = blockIdx.x;         // 256 blocks (16x16 tiles), %8==0
    const int swz = (bid & 7) * 32 + (bid >> 3);
    const int bm0 = (swz >> 4) * 256;
    const int bn0 = (swz & 15) * 256;

    // staging source: thread covers rows r0 and r0+64 of a half-tile,
    // 16 B at swizzled byte-col cs (involution: src-perm == read-perm)
    const int r0 = tid >> 3;                                // 0..63
    const int cs = ((tid & 7) * 16) ^ ((r0 & 7) << 4);      // 0..127
    const _Float16* Asrc = A + (size_t)(bm0 + r0) * IN_F + (cs >> 1);
    const _Float16* Bsrc = B + (size_t)(bn0 + r0) * IN_F + (cs >> 1);
    const int dstoff = wid * 1024;                          // wave-uniform

    // frag-read offsets (swizzled)
    const int lane15 = lane & 15;
    const int swr = (lane & 7) << 4;
    const int c0 = ((lane >> 4) * 16) ^ swr;        // kk=0 byte col
    const int c1 = (64 + (lane >> 4) * 16) ^ swr;   // kk=1
    int rAoff[4], rBoff[2];
#pragma unroll
    for (int mm = 0; mm < 4; ++mm) rAoff[mm] = (wm * 64 + mm * 16 + lane15) * 128;
#pragma unroll
    for (int nn = 0; nn < 2; ++nn) rBoff[nn] = (wn * 32 + nn * 16 + lane15) * 128;

    // aA always holds an A0-half, aB an A1-half; bA a B0-half, bB a B1-half.
    f16x8 aA[4][2], aB[4][2], bA[2][2], bB[2][2];
    f32x4 acc[8][4];
#pragma unroll
    for (int m = 0; m < 8; ++m)
#pragma unroll
        for (int n = 0; n < 4; ++n) acc[m][n] = (f32x4)0.0f;

#define STAGE_A(HALF, KT, BUF) do {                                           \
        const _Float16* s_ = Asrc + (size_t)(HALF) * 128 * IN_F + (KT) * 64;  \
        char* d_ = ldsA + ((BUF) * 2 + (HALF)) * 16384 + dstoff;              \
        GLOAD16(s_, d_);                                                      \
        GLOAD16(s_ + (size_t)64 * IN_F, d_ + 8192); } while (0)

#define STAGE_B(HALF, KT, BUF) do {                                           \
        const _Float16* s_ = Bsrc + (size_t)(HALF) * 128 * IN_F + (KT) * 64;  \
        char* d_ = ldsB + ((BUF) * 2 + (HALF)) * 16384 + dstoff;              \
        GLOAD16(s_, d_);                                                      \
        GLOAD16(s_ + (size_t)64 * IN_F, d_ + 8192); } while (0)

#define RD_A(BUF, QM, DST) do { char* ab_ = ldsA + ((BUF) * 2 + (QM)) * 16384;\
        _Pragma("unroll") for (int mm = 0; mm < 4; ++mm) {                    \
            DST[mm][0] = *(const f16x8*)(ab_ + rAoff[mm] + c0);               \
            DST[mm][1] = *(const f16x8*)(ab_ + rAoff[mm] + c1); } } while (0)

#define RD_B(BUF, QN, DST) do { char* bb_ = ldsB + ((BUF) * 2 + (QN)) * 16384;\
        _Pragma("unroll") for (int nn = 0; nn < 2; ++nn) {                    \
            DST[nn][0] = *(const f16x8*)(bb_ + rBoff[nn] + c0);               \
            DST[nn][1] = *(const f16x8*)(bb_ + rBoff[nn] + c1); } } while (0)

#define MFMA_Q(QM, QN, AQ, BQ)                                                \
        __builtin_amdgcn_s_setprio(1);                                        \
        _Pragma("unroll") for (int mm = 0; mm < 4; ++mm)                      \
        _Pragma("unroll") for (int nn = 0; nn < 2; ++nn)                      \
        _Pragma("unroll") for (int kk = 0; kk < 2; ++kk)                      \
            acc[(QM)*4+mm][(QN)*2+nn] =                                       \
                __builtin_amdgcn_mfma_f32_16x16x32_f16(                       \
                    AQ[mm][kk], BQ[nn][kk], acc[(QM)*4+mm][(QN)*2+nn],0,0,0); \
        __builtin_amdgcn_s_setprio(0);

    // prologue: b0 <- tile0 (A0,B0,B1,A1), b1 <- tile1 (A0,B0,B1, A1 LAST --
    // steady-state retirement sets depend on b1.A1 being the newest).
    STAGE_A(0, 0, 0); STAGE_B(0, 0, 0); STAGE_B(1, 0, 0); STAGE_A(1, 0, 0);
    STAGE_A(0, 1, 1); STAGE_B(0, 1, 1); STAGE_B(1, 1, 1); STAGE_A(1, 1, 1);
    VMW8; BARRIER;                      // retire tile0 (keep b1's 8 loads)
    RD_A(0, 0, aA); RD_B(0, 0, bA);     // tile0 Q00 operands

    for (int t = 0; t < NKT; t += 2) {
        const int k2 = (t + 2) & 63;    // t=62 -> dead restage of K0/K1
        const int k3 = (t + 3) & 63;
        // ---- P0: rd B1b0 -> bB ; mfma Q00(t) ----
        RD_B(0, 1, bB);
        MFMA_Q(0, 0, aA, bA); BARRIER;
        // ---- P1: rd A1b0 -> aB ; st A0(t+2)->b0 ; mfma Q01(t) ----
        RD_A(0, 1, aB); STAGE_A(0, k2, 0);
        MFMA_Q(0, 1, aA, bB); BARRIER;
        // ---- P2: st B0(t+2)->b0 ; mfma Q10(t) ; publish b1.{A0,B0,B1} ----
        STAGE_B(0, k2, 0);
        MFMA_Q(1, 0, aB, bA); VMW6; BARRIER;
        // ---- P3: rd A0b1,B0b1 ; st B1,A1(t+2)->b0 ; mfma Q11(t) ----
        RD_A(1, 0, aA); RD_B(1, 0, bA); STAGE_B(1, k2, 0); STAGE_A(1, k2, 0);
        MFMA_Q(1, 1, aB, bB); BARRIER;
        // ---- P4: rd B1b1 ; mfma Q00(t+1) ; publish b1.A1 ----
        RD_B(1, 1, bB);
        MFMA_Q(0, 0, aA, bA); VMW6; BARRIER;
        // ---- P5: rd A1b1 ; st A0,B0(t+3)->b1 ; mfma Q01(t+1) ----
        RD_A(1, 1, aB); STAGE_A(0, k3, 1); STAGE_B(0, k3, 1);
        MFMA_Q(0, 1, aA, bB); BARRIER;
        // ---- P6: st B1(t+3)->b1 ; mfma Q10(t+1) ; publish b0(t+2) ----
        STAGE_B(1, k3, 1);
        MFMA_Q(1, 0, aB, bA); VMW6; BARRIER;
        // ---- P7: rd A0b0,B0b0 (tile t+2) ; st A1(t+3)->b1 ; mfma Q11(t+1) --
        RD_A(0, 0, aA); RD_B(0, 0, bA); STAGE_A(1, k3, 1);
        MFMA_Q(1, 1, aB, bB); BARRIER;
    }
    asm volatile("s_waitcnt vmcnt(0)" ::: "memory");   // drain dead stages

#pragma unroll
    for (int m = 0; m < 8; ++m) {
        const int Mr = bm0 + (m >> 2) * 128 + wm * 64 + (m & 3) * 16 + (lane >> 4) * 4;
#pragma unroll
        for (int n = 0; n < 4; ++n) {
            const int Nc = bn0 + (n >> 1) * 128 + wn * 32 + (n & 1) * 16 + lane15;
#pragma unroll
            for (int r = 0; r < 4; ++r)
                C[(size_t)(Mr + r) * OUT_F + Nc] = acc[m][n][r];
        }
    }
#undef STAGE_A
#undef STAGE_B
#undef RD_A
#undef RD_B
#undef MFMA_Q
}

// ---------------- fallback: m97-structure GEMM (static 16 KB LDS) ----------
__global__ __launch_bounds__(256, 3)
void gemm_f16(const _Float16* __restrict__ A,
              const _Float16* __restrict__ B,
              float*          __restrict__ C)
{
    __shared__ __align__(16) _Float16 lA[128 * 32];
    __shared__ __align__(16) _Float16 lB[128 * 32];

    const int tid  = threadIdx.x;
    const int lane = tid & 63;
    const int bid = blockIdx.x;
    const int swz = (bid & 7) * 128 + (bid >> 3);
    const int bm0 = (swz >> 5) * 128;
    const int bn0 = (swz & 31) * 128;

    const int sr = tid >> 2;
    const int sc = (tid & 3) * 8;
    const _Float16* Aps = A + (size_t)(bm0 + sr) * IN_F + sc;
    const _Float16* Bps = B + (size_t)(bn0 + sr) * IN_F + sc;
    char* lAb = (char*)lA + (tid & ~63) * 16;
    char* lBb = (char*)lB + (tid & ~63) * 16;

    const int wv = tid >> 6;
    const int wr = (wv >> 1) * 64;
    const int wc = (wv & 1)  * 64;
    const int lr  = lane & 15;
    const int lkb = (lane >> 4) * 16;

    f32x4 acc[4][4];
#pragma unroll
    for (int m = 0; m < 4; ++m)
#pragma unroll
        for (int n = 0; n < 4; ++n) acc[m][n] = (f32x4)0.0f;

    for (int kt = 0; kt < 128; ++kt) {
        __syncthreads();
        {
            const _Float16* ak = Aps + kt * 32;
            const _Float16* bk = Bps + kt * 32;
            GLOAD16(ak, lAb);
            GLOAD16(ak + (size_t)64 * IN_F, lAb + 4096);
            GLOAD16(bk, lBb);
            GLOAD16(bk + (size_t)64 * IN_F, lBb + 4096);
        }
        __syncthreads();

        f16x8 a[4], b[4];
#pragma unroll
        for (int m = 0; m < 4; ++m)
            a[m] = *(const f16x8*)((const char*)lA + (wr + m * 16 + lr) * 64 + lkb);
#pragma unroll
        for (int n = 0; n < 4; ++n)
            b[n] = *(const f16x8*)((const char*)lB + (wc + n * 16 + lr) * 64 + lkb);
#pragma unroll
        for (int m = 0; m < 4; ++m)
#pragma unroll
            for (int n = 0; n < 4; ++n)
                acc[m][n] = __builtin_amdgcn_mfma_f32_16x16x32_f16(
                    a[m], b[n], acc[m][n], 0, 0, 0);
    }

    const int crow = bm0 + wr + (lane >> 4) * 4;
    const int ccol = bn0 + wc + lr;
#pragma unroll
    for (int m = 0; m < 4; ++m)
#pragma unroll
        for (int n = 0; n < 4; ++n)
#pragma unroll
            for (int r = 0; r < 4; ++r)
                C[(size_t)(crow + m * 16 + r) * OUT_F + (ccol + n * 16)]
                    = acc[m][n][r];
}

extern "C" void kernel_launch(void* const* d_in, const int* in_sizes, int n_in,
                              void* d_out, int out_size, void* d_ws, size_t ws_size,
                              hipStream_t stream) {
    (void)in_sizes; (void)n_in; (void)out_size; (void)ws_size;
    const float* x  = (const float*)d_in[0];
    const int*   qw = (const int*)d_in[1];
    const float* s  = (const float*)d_in[2];
    float*       out = (float*)d_out;

    _Float16* xf = (_Float16*)d_ws;
    _Float16* wf = xf + (size_t)OUT_F * IN_F;
    prep<<<dim3(16384), dim3(256), 0, stream>>>(x, qw, s, xf, wf);

    hipError_t e = hipFuncSetAttribute((const void*)gemm_ra,
        hipFuncAttributeMaxDynamicSharedMemorySize, 131072);
    if (e == hipSuccess)
        gemm_ra<<<dim3(256), dim3(512), 131072, stream>>>(xf, wf, out);
    else
        gemm_f16<<<dim3(1024), dim3(256), 0, stream>>>(xf, wf, out);
}

// Round 16
// 135.618 us; speedup vs baseline: 1.0245x; 1.0245x over previous
//
#include <hip/hip_runtime.h>

typedef __attribute__((ext_vector_type(8))) _Float16 f16x8;
typedef __attribute__((ext_vector_type(4))) float    f32x4;
typedef __attribute__((ext_vector_type(4))) int      i32x4;

#define IN_F   4096
#define OUT_F  4096
#define NGRP   32
#define NKT    64          /* K-tiles of 64 */

#define GLOAD16(gsrc, ldst)                                                   \
    __builtin_amdgcn_global_load_lds(                                         \
        (const __attribute__((address_space(1))) unsigned int*)(gsrc),        \
        (__attribute__((address_space(3))) unsigned int*)(ldst), 16, 0, 0)

#define CFENCE  asm volatile("" ::: "memory")
#define BARRIER do { CFENCE; __builtin_amdgcn_s_barrier(); CFENCE; } while (0)
#define VMW6    asm volatile("s_waitcnt vmcnt(6)" ::: "memory")

// ---------------- fused prepass: X fp32->f16 and int4 dequant->f16 ----------
__global__ __launch_bounds__(256)
void prep(const float* __restrict__ X, const int* __restrict__ QW,
          const float* __restrict__ S, _Float16* __restrict__ XF,
          _Float16* __restrict__ WF) {
    if (blockIdx.x < 8192) {
        size_t i = ((size_t)blockIdx.x * 256 + threadIdx.x) * 8;
        f32x4 a = *(const f32x4*)(X + i);
        f32x4 b = *(const f32x4*)(X + i + 4);
        f16x8 h;
        h[0] = (_Float16)a[0]; h[1] = (_Float16)a[1];
        h[2] = (_Float16)a[2]; h[3] = (_Float16)a[3];
        h[4] = (_Float16)b[0]; h[5] = (_Float16)b[1];
        h[6] = (_Float16)b[2]; h[7] = (_Float16)b[3];
        *(f16x8*)(XF + i) = h;
    } else {
        size_t t  = ((size_t)blockIdx.x - 8192) * 256 + threadIdx.x;
        size_t jj = t * 4;                   // int32 index; 2048 per row
        size_t o  = jj >> 11;
        size_t jr = jj & 2047;
        const float s = S[o * NGRP + (jr >> 6)];   // group const across 4 int32
        i32x4 q = *(const i32x4*)(QW + jj);
        f16x8 h;
#pragma unroll
        for (int j = 0; j < 4; ++j) {
            const int v = q[j];
            h[2 * j]     = (_Float16)((float)(((v >> 4) & 15) - 8) * s);
            h[2 * j + 1] = (_Float16)((float)((v & 15) - 8) * s);
        }
        *(f16x8*)(WF + jj * 2) = h;
    }
}

// ---------------- main GEMM: 256^2, BK=64, MERGED phases (2/K-tile) ---------
// Best verified configuration (rounds 10/14): GEMM 117.5-118.0us, MfmaUtil
// 51.4-52.5%, 0 bank conflicts, total ~135us. Per K-tile, 2 phases of 2
// quadrants (32 MFMA) each; 4 barriers per 2 K-tiles. T2 swizzle
// byte^=(row&7)<<4 realized as pre-swizzled global source (linear DMA dest)
// + swizzled ds_read (rule #21; 128B rows -> fully conflict-free).
// Stage plan: PA: A1(t+1)->b1. PB: A0,B0,B1(t+2)->b0. PC: A1(t+2)->b0.
// PD: A0,B0,B1(t+3)->b1. Every stage >=1 barrier after its region's last
// read. VMW6 at PB/PD ends retires exactly the next buffer's 4 stages
// (8 loads), keeps newest 3 stages (6 loads) in flight; the trailing
// barrier publishes all waves' DMA landings before the reads.
__global__ __launch_bounds__(512, 2)
void gemm8p(const _Float16* __restrict__ A,
            const _Float16* __restrict__ B,
            float*          __restrict__ C)
{
    extern __shared__ char LDSc[];
    char* const ldsA = LDSc;
    char* const ldsB = LDSc + 65536;

    const int tid  = threadIdx.x;
    const int lane = tid & 63;
    const int wid  = tid >> 6;
    const int wm   = wid >> 2;          // 0..1
    const int wn   = wid & 3;           // 0..3

    const int bid = blockIdx.x;         // 256 blocks (16x16 tiles), %8==0
    const int swz = (bid & 7) * 32 + (bid >> 3);
    const int bm0 = (swz >> 4) * 256;
    const int bn0 = (swz & 15) * 256;

    // staging source: thread covers rows r0 and r0+64 of a half-tile,
    // 16 B at swizzled byte-col cs (involution: src-perm == read-perm)
    const int r0 = tid >> 3;                                // 0..63
    const int cs = ((tid & 7) * 16) ^ ((r0 & 7) << 4);      // 0..127
    const _Float16* Asrc = A + (size_t)(bm0 + r0) * IN_F + (cs >> 1);
    const _Float16* Bsrc = B + (size_t)(bn0 + r0) * IN_F + (cs >> 1);
    const int dstoff = wid * 1024;                          // wave-uniform

    // frag-read offsets (swizzled)
    const int lane15 = lane & 15;
    const int swr = (lane & 7) << 4;
    const int c0 = ((lane >> 4) * 16) ^ swr;        // kk=0 byte col
    const int c1 = (64 + (lane >> 4) * 16) ^ swr;   // kk=1
    int rAoff[4], rBoff[2];
#pragma unroll
    for (int mm = 0; mm < 4; ++mm) rAoff[mm] = (wm * 64 + mm * 16 + lane15) * 128;
#pragma unroll
    for (int nn = 0; nn < 2; ++nn) rBoff[nn] = (wn * 32 + nn * 16 + lane15) * 128;

    f16x8 afr[4][2], blo[2][2], bhi[2][2];
    f32x4 acc[8][4];
#pragma unroll
    for (int m = 0; m < 8; ++m)
#pragma unroll
        for (int n = 0; n < 4; ++n) acc[m][n] = (f32x4)0.0f;

#define STAGE_A(HALF, KT, BUF) do {                                           \
        const _Float16* s_ = Asrc + (size_t)(HALF) * 128 * IN_F + (KT) * 64;  \
        char* d_ = ldsA + ((BUF) * 2 + (HALF)) * 16384 + dstoff;              \
        GLOAD16(s_, d_);                                                      \
        GLOAD16(s_ + (size_t)64 * IN_F, d_ + 8192); } while (0)

#define STAGE_B(HALF, KT, BUF) do {                                           \
        const _Float16* s_ = Bsrc + (size_t)(HALF) * 128 * IN_F + (KT) * 64;  \
        char* d_ = ldsB + ((BUF) * 2 + (HALF)) * 16384 + dstoff;              \
        GLOAD16(s_, d_);                                                      \
        GLOAD16(s_ + (size_t)64 * IN_F, d_ + 8192); } while (0)

#define RD_A(BUF, QM) do { char* ab_ = ldsA + ((BUF) * 2 + (QM)) * 16384;     \
        _Pragma("unroll") for (int mm = 0; mm < 4; ++mm) {                    \
            afr[mm][0] = *(const f16x8*)(ab_ + rAoff[mm] + c0);               \
            afr[mm][1] = *(const f16x8*)(ab_ + rAoff[mm] + c1); } } while (0)

#define RD_B(BUF, QN, DST) do { char* bb_ = ldsB + ((BUF) * 2 + (QN)) * 16384;\
        _Pragma("unroll") for (int nn = 0; nn < 2; ++nn) {                    \
            DST[nn][0] = *(const f16x8*)(bb_ + rBoff[nn] + c0);               \
            DST[nn][1] = *(const f16x8*)(bb_ + rBoff[nn] + c1); } } while (0)

#define MFMA_Q(QM, QN, BQ)                                                    \
        __builtin_amdgcn_s_setprio(1);                                        \
        _Pragma("unroll") for (int mm = 0; mm < 4; ++mm)                      \
        _Pragma("unroll") for (int nn = 0; nn < 2; ++nn)                      \
        _Pragma("unroll") for (int kk = 0; kk < 2; ++kk)                      \
            acc[(QM)*4+mm][(QN)*2+nn] =                                       \
                __builtin_amdgcn_mfma_f32_16x16x32_f16(                       \
                    afr[mm][kk], BQ[nn][kk], acc[(QM)*4+mm][(QN)*2+nn],0,0,0);\
        __builtin_amdgcn_s_setprio(0);

    // prologue: K0 full -> buf0, K1 {A0,B0,B1} -> buf1 (7 stages, 14 loads).
    STAGE_A(0, 0, 0); STAGE_B(0, 0, 0); STAGE_B(1, 0, 0); STAGE_A(1, 0, 0);
    STAGE_A(0, 1, 1); STAGE_B(0, 1, 1); STAGE_B(1, 1, 1);
    VMW6; BARRIER;

    for (int t = 0; t < NKT; t += 2) {
        const int k2 = (t + 2) & 63;   // t=62 -> dead restage of K0/K1
        const int k3 = (t + 3) & 63;
        // ---- PA: quadrants Q00,Q01 of K-tile t (buf0) ----
        RD_A(0, 0); RD_B(0, 0, blo); RD_B(0, 1, bhi);
        STAGE_A(1, t + 1, 1);
        MFMA_Q(0, 0, blo); MFMA_Q(0, 1, bhi);
        BARRIER;
        // ---- PB: quadrants Q10,Q11 (buf0) ; stage t+2 A0/B0/B1 -> b0 ----
        RD_A(0, 1);
        STAGE_A(0, k2, 0); STAGE_B(0, k2, 0); STAGE_B(1, k2, 0);
        MFMA_Q(1, 0, blo); MFMA_Q(1, 1, bhi);
        VMW6; BARRIER;      // retires buf1 K-tile t+1; barrier publishes
        // ---- PC: quadrants Q00,Q01 of K-tile t+1 (buf1) ----
        RD_A(1, 0); RD_B(1, 0, blo); RD_B(1, 1, bhi);
        STAGE_A(1, k2, 0);
        MFMA_Q(0, 0, blo); MFMA_Q(0, 1, bhi);
        BARRIER;
        // ---- PD: quadrants Q10,Q11 (buf1) ; stage t+3 A0/B0/B1 -> b1 ----
        RD_A(1, 1);
        STAGE_A(0, k3, 1); STAGE_B(0, k3, 1); STAGE_B(1, k3, 1);
        MFMA_Q(1, 0, blo); MFMA_Q(1, 1, bhi);
        VMW6; BARRIER;      // retires buf0 K-tile t+2
    }
    asm volatile("s_waitcnt vmcnt(0)" ::: "memory");   // drain DMA before end

#pragma unroll
    for (int m = 0; m < 8; ++m) {
        const int Mr = bm0 + (m >> 2) * 128 + wm * 64 + (m & 3) * 16 + (lane >> 4) * 4;
#pragma unroll
        for (int n = 0; n < 4; ++n) {
            const int Nc = bn0 + (n >> 1) * 128 + wn * 32 + (n & 1) * 16 + lane15;
#pragma unroll
            for (int r = 0; r < 4; ++r)
                C[(size_t)(Mr + r) * OUT_F + Nc] = acc[m][n][r];
        }
    }
#undef STAGE_A
#undef STAGE_B
#undef RD_A
#undef RD_B
#undef MFMA_Q
}

// ---------------- fallback: m97-structure GEMM (static 16 KB LDS) ----------
__global__ __launch_bounds__(256, 3)
void gemm_f16(const _Float16* __restrict__ A,
              const _Float16* __restrict__ B,
              float*          __restrict__ C)
{
    __shared__ __align__(16) _Float16 lA[128 * 32];
    __shared__ __align__(16) _Float16 lB[128 * 32];

    const int tid  = threadIdx.x;
    const int lane = tid & 63;
    const int bid = blockIdx.x;
    const int swz = (bid & 7) * 128 + (bid >> 3);
    const int bm0 = (swz >> 5) * 128;
    const int bn0 = (swz & 31) * 128;

    const int sr = tid >> 2;
    const int sc = (tid & 3) * 8;
    const _Float16* Aps = A + (size_t)(bm0 + sr) * IN_F + sc;
    const _Float16* Bps = B + (size_t)(bn0 + sr) * IN_F + sc;
    char* lAb = (char*)lA + (tid & ~63) * 16;
    char* lBb = (char*)lB + (tid & ~63) * 16;

    const int wv = tid >> 6;
    const int wr = (wv >> 1) * 64;
    const int wc = (wv & 1)  * 64;
    const int lr  = lane & 15;
    const int lkb = (lane >> 4) * 16;

    f32x4 acc[4][4];
#pragma unroll
    for (int m = 0; m < 4; ++m)
#pragma unroll
        for (int n = 0; n < 4; ++n) acc[m][n] = (f32x4)0.0f;

    for (int kt = 0; kt < 128; ++kt) {
        __syncthreads();
        {
            const _Float16* ak = Aps + kt * 32;
            const _Float16* bk = Bps + kt * 32;
            GLOAD16(ak, lAb);
            GLOAD16(ak + (size_t)64 * IN_F, lAb + 4096);
            GLOAD16(bk, lBb);
            GLOAD16(bk + (size_t)64 * IN_F, lBb + 4096);
        }
        __syncthreads();

        f16x8 a[4], b[4];
#pragma unroll
        for (int m = 0; m < 4; ++m)
            a[m] = *(const f16x8*)((const char*)lA + (wr + m * 16 + lr) * 64 + lkb);
#pragma unroll
        for (int n = 0; n < 4; ++n)
            b[n] = *(const f16x8*)((const char*)lB + (wc + n * 16 + lr) * 64 + lkb);
#pragma unroll
        for (int m = 0; m < 4; ++m)
#pragma unroll
            for (int n = 0; n < 4; ++n)
                acc[m][n] = __builtin_amdgcn_mfma_f32_16x16x32_f16(
                    a[m], b[n], acc[m][n], 0, 0, 0);
    }

    const int crow = bm0 + wr + (lane >> 4) * 4;
    const int ccol = bn0 + wc + lr;
#pragma unroll
    for (int m = 0; m < 4; ++m)
#pragma unroll
        for (int n = 0; n < 4; ++n)
#pragma unroll
            for (int r = 0; r < 4; ++r)
                C[(size_t)(crow + m * 16 + r) * OUT_F + (ccol + n * 16)]
                    = acc[m][n][r];
}

extern "C" void kernel_launch(void* const* d_in, const int* in_sizes, int n_in,
                              void* d_out, int out_size, void* d_ws, size_t ws_size,
                              hipStream_t stream) {
    (void)in_sizes; (void)n_in; (void)out_size; (void)ws_size;
    const float* x  = (const float*)d_in[0];
    const int*   qw = (const int*)d_in[1];
    const float* s  = (const float*)d_in[2];
    float*       out = (float*)d_out;

    _Float16* xf = (_Float16*)d_ws;
    _Float16* wf = xf + (size_t)OUT_F * IN_F;
    prep<<<dim3(16384), dim3(256), 0, stream>>>(x, qw, s, xf, wf);

    hipError_t e = hipFuncSetAttribute((const void*)gemm8p,
        hipFuncAttributeMaxDynamicSharedMemorySize, 131072);
    if (e == hipSuccess)
        gemm8p<<<dim3(256), dim3(512), 131072, stream>>>(xf, wf, out);
    else
        gemm_f16<<<dim3(1024), dim3(256), 0, stream>>>(xf, wf, out);
}